// Round 17
// baseline (194.852 us; speedup 1.0000x reference)
//
#include <hip/hip_runtime.h>

#define FIELDS  100000
#define FACTORS 16
#define BATCH   1024
#define BT      8                      // batch rows per block
#define NCHUNK  8                      // chunk == bid&7 -> XCD-pinned W slice
#define FPC     (FIELDS / NCHUNK)      // 12500
#define BLOCK   256
#define NSPANF  48                     // full 256-field pack spans (12288)
#define WPR     392                    // mask words per row (12544 bits >= 12500)
#define TF      512                    // fields per compute tile
#define NTF     (FPC / TF)             // 24
#define TAILPG  ((FPC - NTF * TF) / 4) // 53 (212 = 53*4 tail fields)

// spread byte bits to every 4th bit of a word: bit i -> bit 4i
__device__ __forceinline__ unsigned spread8(unsigned x) {
    x = (x | (x << 12)) & 0x000F000Fu;
    x = (x | (x << 6))  & 0x03030303u;
    x = (x | (x << 3))  & 0x11111111u;
    return x;
}

// Phase A: block bit-packs its 8 rows x 12500 fields (400KB, coalesced max-MLP
// burst) into lmask[8][392] (12.5KB LDS). Phase B: barrier-free compute — W
// from L2 + ds_read_b32 mask words + FMA chains. x0 bytes touched exactly once.
__global__ __launch_bounds__(BLOCK, 4) void fm_partial(
    const int* __restrict__ x0, const float* __restrict__ W,
    float* __restrict__ ws)
{
    __shared__ unsigned lmask[BT][WPR];     // 12.5 KB
    __shared__ float red[4][BT][17];        // 2.2 KB

    const int t     = threadIdx.x;
    const int bid   = blockIdx.x;
    const int rg    = bid >> 3;             // 0..127
    const int chunk = bid & (NCHUNK - 1);   // 0..7
    const int b0    = rg * BT;
    const int fbeg  = chunk * FPC;

    const int qr   = t & 3;                 // factor quarter
    const int pg   = t >> 2;                // field group 0..63
    const int lane = t & 63;
    const int wv   = t >> 6;

    // ================= Phase A: bit-pack x0 -> LDS =================
    {
        const int lr0 = 2 * wv, lr1 = lr0 + 1;
        const int* xr0 = x0 + (size_t)(b0 + lr0) * FIELDS + fbeg;
        const int* xr1 = x0 + (size_t)(b0 + lr1) * FIELDS + fbeg;
        const int sh8 = 8 * (lane & 7);

#define PACKW(xv, lrow, ss) do {                                            \
        const unsigned long long B0 = __ballot((xv).x > 0);                 \
        const unsigned long long B1 = __ballot((xv).y > 0);                 \
        const unsigned long long B2 = __ballot((xv).z > 0);                 \
        const unsigned long long B3 = __ballot((xv).w > 0);                 \
        const unsigned word = spread8((unsigned)(B0 >> sh8) & 0xFFu)        \
                      | (spread8((unsigned)(B1 >> sh8) & 0xFFu) << 1)       \
                      | (spread8((unsigned)(B2 >> sh8) & 0xFFu) << 2)       \
                      | (spread8((unsigned)(B3 >> sh8) & 0xFFu) << 3);      \
        if (lane < 8) lmask[lrow][(ss) * 8 + lane] = word;                  \
    } while (0)

        // full spans, batched 4 deep x 2 rows = 8 independent loads in flight
#pragma unroll 1
        for (int s = 0; s < NSPANF; s += 4) {
            int4 va[4], vb[4];
#pragma unroll
            for (int i = 0; i < 4; ++i) {
                va[i] = *(const int4*)(xr0 + (s + i) * 256 + lane * 4);
                vb[i] = *(const int4*)(xr1 + (s + i) * 256 + lane * 4);
            }
#pragma unroll
            for (int i = 0; i < 4; ++i) {
                PACKW(va[i], lr0, s + i);
                PACKW(vb[i], lr1, s + i);
            }
        }
        // tail span: 212 fields (lanes 0..52 fully valid; 212 = 53*4)
        {
            const bool v  = (lane < 53);
            const int off = 12288 + (v ? lane * 4 : 0);
            int4 xa = *(const int4*)(xr0 + off);
            int4 xb = *(const int4*)(xr1 + off);
            if (!v) { xa.x = xa.y = xa.z = xa.w = 0; xb.x = xb.y = xb.z = xb.w = 0; }
            PACKW(xa, lr0, NSPANF);         // words 384..391 (incl. zero pad)
            PACKW(xb, lr1, NSPANF);
        }
#undef PACKW
    }
    __syncthreads();                        // masks ready; read-only hereafter

    // ================= Phase B: barrier-free compute =================
    float acc[BT][4], qac[BT];
#pragma unroll
    for (int r = 0; r < BT; ++r) {
        qac[r] = 0.f;
#pragma unroll
        for (int j = 0; j < 4; ++j) acc[r][j] = 0.f;
    }

    const char* Wb = (const char*)W;
    const unsigned wq    = (unsigned)qr * 16u;
    const unsigned wbase = (unsigned)(fbeg + pg * 4) * 64u + wq;
    const int pg8 = pg >> 3;                // word sub-index within half-tile
    const int bb  = (pg * 4) & 31;          // bit base (tile-invariant)

    // FM body: W rows p0..p3 + masks from word mw per batch row
#define FMHALF(p0, p1, p2, p3, WIDX)                                        \
    do {                                                                    \
        const float s0 = fmaf(p0.x, p0.x, fmaf(p0.y, p0.y, fmaf(p0.z, p0.z, p0.w * p0.w))); \
        const float s1 = fmaf(p1.x, p1.x, fmaf(p1.y, p1.y, fmaf(p1.z, p1.z, p1.w * p1.w))); \
        const float s2 = fmaf(p2.x, p2.x, fmaf(p2.y, p2.y, fmaf(p2.z, p2.z, p2.w * p2.w))); \
        const float s3 = fmaf(p3.x, p3.x, fmaf(p3.y, p3.y, fmaf(p3.z, p3.z, p3.w * p3.w))); \
        _Pragma("unroll")                                                   \
        for (int r = 0; r < BT; ++r) {                                      \
            const unsigned mw = lmask[r][WIDX];                             \
            const float m0 = ((mw >> (bb + 0)) & 1u) ? 1.f : 0.f;           \
            const float m1 = ((mw >> (bb + 1)) & 1u) ? 1.f : 0.f;           \
            const float m2 = ((mw >> (bb + 2)) & 1u) ? 1.f : 0.f;           \
            const float m3 = ((mw >> (bb + 3)) & 1u) ? 1.f : 0.f;           \
            qac[r]    = fmaf(m0, s0,   fmaf(m1, s1,   fmaf(m2, s2,   fmaf(m3, s3,   qac[r])))); \
            acc[r][0] = fmaf(m0, p0.x, fmaf(m1, p1.x, fmaf(m2, p2.x, fmaf(m3, p3.x, acc[r][0])))); \
            acc[r][1] = fmaf(m0, p0.y, fmaf(m1, p1.y, fmaf(m2, p2.y, fmaf(m3, p3.y, acc[r][1])))); \
            acc[r][2] = fmaf(m0, p0.z, fmaf(m1, p1.z, fmaf(m2, p2.z, fmaf(m3, p3.z, acc[r][2])))); \
            acc[r][3] = fmaf(m0, p0.w, fmaf(m1, p1.w, fmaf(m2, p2.w, fmaf(m3, p3.w, acc[r][3])))); \
        }                                                                   \
    } while (0)

#pragma unroll 1
    for (int tl = 0; tl < NTF; ++tl) {
        const unsigned wB = wbase + (unsigned)tl * (TF * 64u);
        const float4 wa0 = *(const float4*)(Wb + wB);
        const float4 wa1 = *(const float4*)(Wb + wB + 64u);
        const float4 wa2 = *(const float4*)(Wb + wB + 128u);
        const float4 wa3 = *(const float4*)(Wb + wB + 192u);
        const float4 wb0 = *(const float4*)(Wb + wB + 16384u);
        const float4 wb1 = *(const float4*)(Wb + wB + 16384u + 64u);
        const float4 wb2 = *(const float4*)(Wb + wB + 16384u + 128u);
        const float4 wb3 = *(const float4*)(Wb + wB + 16384u + 192u);
        const int widx0 = tl * 16 + pg8;    // half 0 word
        FMHALF(wa0, wa1, wa2, wa3, widx0);
        FMHALF(wb0, wb1, wb2, wb3, widx0 + 8);
    }

    // tail: 212 fields, per-lane-uniform validity
    {
        const bool valid = (pg < TAILPG);
        const int  pgc   = valid ? pg : (TAILPG - 1);
        const unsigned fb = (unsigned)(fbeg + NTF * TF + pgc * 4);
        const unsigned wT = fb * 64u + wq;
        float4 w0 = *(const float4*)(Wb + wT);
        float4 w1 = *(const float4*)(Wb + wT + 64u);
        float4 w2 = *(const float4*)(Wb + wT + 128u);
        float4 w3 = *(const float4*)(Wb + wT + 192u);
        if (!valid) {                       // zero W => zero contribution
            w0.x=w0.y=w0.z=w0.w=0.f; w1.x=w1.y=w1.z=w1.w=0.f;
            w2.x=w2.y=w2.z=w2.w=0.f; w3.x=w3.y=w3.z=w3.w=0.f;
        }
        const int widxT = NTF * 16 + (pgc >> 3);       // 384 + pgc>>3
        const int bbT   = (pgc * 4) & 31;
#define bb bbT
        FMHALF(w0, w1, w2, w3, widxT);
#undef bb
    }
#undef FMHALF

    // ---- wave reduce ----
    // acc: sum lanes sharing qr (xor 4..32). qac: sum ALL 64 lanes — each lane
    // accumulated only its own quarter's ssq, so q is counted exactly once.
#pragma unroll
    for (int r = 0; r < BT; ++r) {
#pragma unroll
        for (int off = 4; off < 64; off <<= 1) {
            acc[r][0] += __shfl_xor(acc[r][0], off);
            acc[r][1] += __shfl_xor(acc[r][1], off);
            acc[r][2] += __shfl_xor(acc[r][2], off);
            acc[r][3] += __shfl_xor(acc[r][3], off);
        }
#pragma unroll
        for (int off = 1; off < 64; off <<= 1)
            qac[r] += __shfl_xor(qac[r], off);
    }

    if (lane < 4) {                         // lane l holds quarter l
#pragma unroll
        for (int r = 0; r < BT; ++r) {
#pragma unroll
            for (int j = 0; j < 4; ++j)
                red[wv][r][lane * 4 + j] = acc[r][j];
            if (lane == 0) red[wv][r][16] = qac[r];
        }
    }
    __syncthreads();
    if (t < BT * 17) {
        const int r = t / 17;
        const int j = t % 17;
        const float v = red[0][r][j] + red[1][r][j] + red[2][r][j] + red[3][r][j];
        ws[((size_t)(b0 + r) * NCHUNK + chunk) * 17 + j] = v;
    }
}

__global__ __launch_bounds__(BLOCK) void fm_final(
    const float* __restrict__ ws, float* __restrict__ out)
{
    const int b = blockIdx.x * BLOCK + threadIdx.x;
    if (b < BATCH) {
        const float* pbase = ws + (size_t)b * NCHUNK * 17;
        float s[17];
#pragma unroll
        for (int j = 0; j < 17; ++j) s[j] = 0.f;
#pragma unroll
        for (int c = 0; c < NCHUNK; ++c)
#pragma unroll
            for (int j = 0; j < 17; ++j) s[j] += pbase[c * 17 + j];
        float ss = 0.f;
#pragma unroll
        for (int k = 0; k < FACTORS; ++k) ss += s[k] * s[k];
        out[b] = 0.5f * (ss - s[16]);
    }
}

extern "C" void kernel_launch(void* const* d_in, const int* in_sizes, int n_in,
                              void* d_out, int out_size, void* d_ws, size_t ws_size,
                              hipStream_t stream)
{
    const int*   x0 = (const int*)d_in[0];
    const float* W  = (const float*)d_in[1];
    float* out = (float*)d_out;
    float* ws  = (float*)d_ws;   // [1024][8][17] floats, every slot written

    fm_partial<<<dim3((BATCH / BT) * NCHUNK), dim3(BLOCK), 0, stream>>>(x0, W, ws);
    fm_final<<<dim3((BATCH + BLOCK - 1) / BLOCK), dim3(BLOCK), 0, stream>>>(ws, out);
}

// Round 18
// 142.499 us; speedup vs baseline: 1.3674x; 1.3674x over previous
//
#include <hip/hip_runtime.h>

#define FIELDS  100000
#define FACTORS 16
#define BATCH   1024
#define BT      4                      // batch rows per block (R18: halved for TLP)
#define NCHUNK  8                      // chunk == bid&7 -> XCD-pinned W slice
#define FPC     (FIELDS / NCHUNK)      // 12500
#define BLOCK   256
#define TF      512                    // fields per tile
#define NTF     (FPC / TF)             // 24 full tiles = 12288 fields
#define TAILPG  ((FPC - NTF * TF) / 4) // 53 (212 tail fields = 53*4)
#define NBUF    2

typedef __attribute__((address_space(1))) const void gvoid;
typedef __attribute__((address_space(3))) void lvoid;

// R18 = R14 skeleton with BT=4: acc state halves (~20 regs) -> live ~80,
// 6 waves/SIMD expected (vs R14's 4). Grid 2048 blocks. LDS 16KB xbuf.
// Ledger per iter (uniform): at wait, outstanding = S(tl)[2] + W(tl)[8] = 10;
// vmcnt(8) retires exactly S(tl), keeps W in flight; barrier; STAGE(tl+1)[2];
// FMAs consume W(tl) (compiler waits retire W heads; S(tl+1), issued after
// W(tl), stays in flight until iter tl+1's vmcnt(8)).
__global__ __launch_bounds__(BLOCK, 4) void fm_partial(
    const int* __restrict__ x0, const float* __restrict__ W,
    float* __restrict__ ws)
{
    __shared__ __align__(16) int xbuf[NBUF][BT][TF];   // 16 KB
    __shared__ float red[4][BT][17];                   // 1.1 KB

    const int t     = threadIdx.x;
    const int bid   = blockIdx.x;
    const int rg    = bid >> 3;               // 0..255
    const int chunk = bid & (NCHUNK - 1);     // 0..7
    const int b0    = rg * BT;
    const int fbeg  = chunk * FPC;

    const int qr   = t & 3;                   // factor quarter
    const int pg   = t >> 2;                  // field group 0..63
    const int lane = t & 63;
    const int wv   = t >> 6;

    float acc[BT][4], qac[BT];
#pragma unroll
    for (int r = 0; r < BT; ++r) {
        qac[r] = 0.f;
#pragma unroll
        for (int j = 0; j < 4; ++j) acc[r][j] = 0.f;
    }

    const char* x0b = (const char*)x0;
    const char* Wb  = (const char*)W;

    // staging: wave wv owns row wv; per tile 1 row x 2KB = 2 x 1KB instrs.
    const unsigned sb0 = ((unsigned)(b0 + wv) * FIELDS + (unsigned)fbeg) * 4u
                       + (unsigned)lane * 16u;
    char* const l0 = (char*)&xbuf[0][wv][0] + lane * 16;

#define STAGE(buf, tile) do {                                               \
        const unsigned _so = (unsigned)(tile) * (TF * 4u);                  \
        __builtin_amdgcn_global_load_lds((gvoid*)(x0b + (sb0 + _so)),       \
            (lvoid*)(l0 + (buf) * (BT * TF * 4)), 16, 0, 0);                \
        __builtin_amdgcn_global_load_lds((gvoid*)(x0b + (sb0 + _so + 1024u)),\
            (lvoid*)(l0 + (buf) * (BT * TF * 4) + 1024), 16, 0, 0);         \
    } while (0)

    // FM body over W rows p0..p3 (plain identifiers, no token pasting)
#define FMTILE(p0, p1, p2, p3, BUFEXPR)                                     \
    do {                                                                    \
        const float s0 = fmaf(p0.x, p0.x, fmaf(p0.y, p0.y, fmaf(p0.z, p0.z, p0.w * p0.w))); \
        const float s1 = fmaf(p1.x, p1.x, fmaf(p1.y, p1.y, fmaf(p1.z, p1.z, p1.w * p1.w))); \
        const float s2 = fmaf(p2.x, p2.x, fmaf(p2.y, p2.y, fmaf(p2.z, p2.z, p2.w * p2.w))); \
        const float s3 = fmaf(p3.x, p3.x, fmaf(p3.y, p3.y, fmaf(p3.z, p3.z, p3.w * p3.w))); \
        _Pragma("unroll")                                                   \
        for (int r = 0; r < BT; ++r) {                                      \
            const int4 xv = BUFEXPR;                                        \
            const float m0 = (float)xv.x, m1 = (float)xv.y;                 \
            const float m2 = (float)xv.z, m3 = (float)xv.w;                 \
            qac[r]    = fmaf(m0, s0,   fmaf(m1, s1,   fmaf(m2, s2,   fmaf(m3, s3,   qac[r])))); \
            acc[r][0] = fmaf(m0, p0.x, fmaf(m1, p1.x, fmaf(m2, p2.x, fmaf(m3, p3.x, acc[r][0])))); \
            acc[r][1] = fmaf(m0, p0.y, fmaf(m1, p1.y, fmaf(m2, p2.y, fmaf(m3, p3.y, acc[r][1])))); \
            acc[r][2] = fmaf(m0, p0.z, fmaf(m1, p1.z, fmaf(m2, p2.z, fmaf(m3, p3.z, acc[r][2])))); \
            acc[r][3] = fmaf(m0, p0.w, fmaf(m1, p1.w, fmaf(m2, p2.w, fmaf(m3, p3.w, acc[r][3])))); \
        }                                                                   \
    } while (0)

    const unsigned wq = (unsigned)qr * 16u;
    // W byte base for (tile-local field pg*4); half h adds h*256 fields = 16384B
    const unsigned wbase = (unsigned)(fbeg + pg * 4) * 64u + wq;

    STAGE(0, 0);

#pragma unroll 1
    for (int tl = 0; tl < NTF; ++tl) {
        // ---- all 8 W loads for this tile, issued before the wait ----
        const unsigned wB = wbase + (unsigned)tl * (TF * 64u);
        const float4 wa0 = *(const float4*)(Wb + wB);
        const float4 wa1 = *(const float4*)(Wb + wB + 64u);
        const float4 wa2 = *(const float4*)(Wb + wB + 128u);
        const float4 wa3 = *(const float4*)(Wb + wB + 192u);
        const float4 wb0 = *(const float4*)(Wb + wB + 16384u);
        const float4 wb1 = *(const float4*)(Wb + wB + 16384u + 64u);
        const float4 wb2 = *(const float4*)(Wb + wB + 16384u + 128u);
        const float4 wb3 = *(const float4*)(Wb + wB + 16384u + 192u);

        // retire S(tl) (2 ops), keep W(tl) (8 ops) in flight — uniform count
        asm volatile("s_waitcnt vmcnt(8)" ::: "memory");
        __builtin_amdgcn_s_barrier();             // tile ready + buf-reuse guard
        __builtin_amdgcn_sched_barrier(0);

        if (tl + 1 < NTF) STAGE((tl + 1) & 1, tl + 1);
        __builtin_amdgcn_sched_barrier(0);        // pin S before later VMEM

        const int buf = tl & 1;
        FMTILE(wa0, wa1, wa2, wa3, (*(const int4*)&xbuf[buf][r][pg * 4]));
        FMTILE(wb0, wb1, wb2, wb3, (*(const int4*)&xbuf[buf][r][256 + pg * 4]));
        // no trailing sched_barrier: next-iter W loads may interleave with FMAs
    }

    // ---- tail: 212 fields, per-lane-uniform validity (212 = 53*4) ----
    {
        const bool valid = (pg < TAILPG);
        const int  pgc   = valid ? pg : (TAILPG - 1);
        const unsigned fb = (unsigned)(fbeg + NTF * TF + pgc * 4);
        const unsigned wT = fb * 64u + wq;
        float4 w0 = *(const float4*)(Wb + wT);
        float4 w1 = *(const float4*)(Wb + wT + 64u);
        float4 w2 = *(const float4*)(Wb + wT + 128u);
        float4 w3 = *(const float4*)(Wb + wT + 192u);
        if (!valid) {                             // zero W => zero contribution
            w0.x=w0.y=w0.z=w0.w=0.f; w1.x=w1.y=w1.z=w1.w=0.f;
            w2.x=w2.y=w2.z=w2.w=0.f; w3.x=w3.y=w3.z=w3.w=0.f;
        }
        FMTILE(w0, w1, w2, w3,
               (*(const int4*)(x0b + ((unsigned)(b0 + r) * FIELDS + fb) * 4u)));
    }

    // ---- wave reduce ----
    // acc: sum lanes sharing qr (xor 4..32). qac: sum ALL 64 lanes — each lane
    // accumulated only its own quarter's ssq, so q is counted exactly once.
#pragma unroll
    for (int r = 0; r < BT; ++r) {
#pragma unroll
        for (int off = 4; off < 64; off <<= 1) {
            acc[r][0] += __shfl_xor(acc[r][0], off);
            acc[r][1] += __shfl_xor(acc[r][1], off);
            acc[r][2] += __shfl_xor(acc[r][2], off);
            acc[r][3] += __shfl_xor(acc[r][3], off);
        }
#pragma unroll
        for (int off = 1; off < 64; off <<= 1)
            qac[r] += __shfl_xor(qac[r], off);
    }

    if (lane < 4) {                               // lane l holds quarter l
#pragma unroll
        for (int r = 0; r < BT; ++r) {
#pragma unroll
            for (int j = 0; j < 4; ++j)
                red[wv][r][lane * 4 + j] = acc[r][j];
            if (lane == 0) red[wv][r][16] = qac[r];
        }
    }
    __syncthreads();
    if (t < BT * 17) {
        const int r = t / 17;
        const int j = t % 17;
        const float v = red[0][r][j] + red[1][r][j] + red[2][r][j] + red[3][r][j];
        ws[((size_t)(b0 + r) * NCHUNK + chunk) * 17 + j] = v;
    }
#undef STAGE
#undef FMTILE
}

__global__ __launch_bounds__(BLOCK) void fm_final(
    const float* __restrict__ ws, float* __restrict__ out)
{
    const int b = blockIdx.x * BLOCK + threadIdx.x;
    if (b < BATCH) {
        const float* pbase = ws + (size_t)b * NCHUNK * 17;
        float s[17];
#pragma unroll
        for (int j = 0; j < 17; ++j) s[j] = 0.f;
#pragma unroll
        for (int c = 0; c < NCHUNK; ++c)
#pragma unroll
            for (int j = 0; j < 17; ++j) s[j] += pbase[c * 17 + j];
        float ss = 0.f;
#pragma unroll
        for (int k = 0; k < FACTORS; ++k) ss += s[k] * s[k];
        out[b] = 0.5f * (ss - s[16]);
    }
}

extern "C" void kernel_launch(void* const* d_in, const int* in_sizes, int n_in,
                              void* d_out, int out_size, void* d_ws, size_t ws_size,
                              hipStream_t stream)
{
    const int*   x0 = (const int*)d_in[0];
    const float* W  = (const float*)d_in[1];
    float* out = (float*)d_out;
    float* ws  = (float*)d_ws;   // [1024][8][17] floats, every slot written

    fm_partial<<<dim3((BATCH / BT) * NCHUNK), dim3(BLOCK), 0, stream>>>(x0, W, ws);
    fm_final<<<dim3((BATCH + BLOCK - 1) / BLOCK), dim3(BLOCK), 0, stream>>>(ws, out);
}

// Round 19
// 111.561 us; speedup vs baseline: 1.7466x; 1.2773x over previous
//
#include <hip/hip_runtime.h>

#define FIELDS  100000
#define FACTORS 16
#define BATCH   1024
#define BT      8                      // batch rows per block
#define NCHUNK  8                      // chunk == bid&7 -> XCD-pinned W slice
#define FPC     (FIELDS / NCHUNK)      // 12500
#define BLOCK   256
#define TF      512                    // fields per tile
#define NTF     (FPC / TF)             // 24 full tiles = 12288 fields
#define TAILPG  ((FPC - NTF * TF) / 4) // 53 (212 tail fields = 53*4)
#define NBUF    2

typedef __attribute__((address_space(1))) const void gvoid;
typedef __attribute__((address_space(3))) void lvoid;

// Champion (R14, 111.8us): TF=512, NBUF=2, BT=8, one barrier per tile.
// Ledger per iter: W(tl)[8] issued first; vmcnt(8) retires S(tl)[4] and keeps
// W(tl) in flight; s_barrier (tile ready + buf-reuse guard); STAGE(tl+1)[4];
// FMAs (compiler's W-consume waits retire W heads; S(tl+1) stays in flight
// until the next iter's vmcnt(8)). The explicit vmcnt(8) is LOAD-BEARING:
// raw s_barrier does not drain vmcnt.
__global__ __launch_bounds__(BLOCK, 4) void fm_partial(
    const int* __restrict__ x0, const float* __restrict__ W,
    float* __restrict__ ws)
{
    __shared__ __align__(16) int xbuf[NBUF][BT][TF];   // 32 KB
    __shared__ float red[4][BT][17];                   // 2.2 KB

    const int t     = threadIdx.x;
    const int bid   = blockIdx.x;
    const int rg    = bid >> 3;               // 0..127
    const int chunk = bid & (NCHUNK - 1);     // 0..7
    const int b0    = rg * BT;
    const int fbeg  = chunk * FPC;

    const int qr   = t & 3;                   // factor quarter
    const int pg   = t >> 2;                  // field group 0..63
    const int lane = t & 63;
    const int wv   = t >> 6;

    float acc[BT][4], qac[BT];
#pragma unroll
    for (int r = 0; r < BT; ++r) {
        qac[r] = 0.f;
#pragma unroll
        for (int j = 0; j < 4; ++j) acc[r][j] = 0.f;
    }

    const char* x0b = (const char*)x0;
    const char* Wb  = (const char*)W;

    // staging: wave wv owns rows {2wv, 2wv+1}; per tile 2 rows x 2 KB =
    // 4 x 1KB gload_lds instrs per wave. All addresses in-bounds (no clamps).
    const int r0 = 2 * wv, r1 = r0 + 1;
    const unsigned sb0 = ((unsigned)(b0 + r0) * FIELDS + (unsigned)fbeg) * 4u
                       + (unsigned)lane * 16u;
    const unsigned sb1 = sb0 + FIELDS * 4u;
    char* const l0 = (char*)&xbuf[0][r0][0] + lane * 16;
    char* const l1 = (char*)&xbuf[0][r1][0] + lane * 16;

#define STAGE(buf, tile) do {                                               \
        const unsigned _so = (unsigned)(tile) * (TF * 4u);                  \
        __builtin_amdgcn_global_load_lds((gvoid*)(x0b + (sb0 + _so)),       \
            (lvoid*)(l0 + (buf) * (BT * TF * 4)), 16, 0, 0);                \
        __builtin_amdgcn_global_load_lds((gvoid*)(x0b + (sb0 + _so + 1024u)),\
            (lvoid*)(l0 + (buf) * (BT * TF * 4) + 1024), 16, 0, 0);         \
        __builtin_amdgcn_global_load_lds((gvoid*)(x0b + (sb1 + _so)),       \
            (lvoid*)(l1 + (buf) * (BT * TF * 4)), 16, 0, 0);                \
        __builtin_amdgcn_global_load_lds((gvoid*)(x0b + (sb1 + _so + 1024u)),\
            (lvoid*)(l1 + (buf) * (BT * TF * 4) + 1024), 16, 0, 0);         \
    } while (0)

    // FM body over W rows p0..p3 (plain identifiers, no token pasting)
#define FMTILE(p0, p1, p2, p3, BUFEXPR)                                     \
    do {                                                                    \
        const float s0 = fmaf(p0.x, p0.x, fmaf(p0.y, p0.y, fmaf(p0.z, p0.z, p0.w * p0.w))); \
        const float s1 = fmaf(p1.x, p1.x, fmaf(p1.y, p1.y, fmaf(p1.z, p1.z, p1.w * p1.w))); \
        const float s2 = fmaf(p2.x, p2.x, fmaf(p2.y, p2.y, fmaf(p2.z, p2.z, p2.w * p2.w))); \
        const float s3 = fmaf(p3.x, p3.x, fmaf(p3.y, p3.y, fmaf(p3.z, p3.z, p3.w * p3.w))); \
        _Pragma("unroll")                                                   \
        for (int r = 0; r < BT; ++r) {                                      \
            const int4 xv = BUFEXPR;                                        \
            const float m0 = (float)xv.x, m1 = (float)xv.y;                 \
            const float m2 = (float)xv.z, m3 = (float)xv.w;                 \
            qac[r]    = fmaf(m0, s0,   fmaf(m1, s1,   fmaf(m2, s2,   fmaf(m3, s3,   qac[r])))); \
            acc[r][0] = fmaf(m0, p0.x, fmaf(m1, p1.x, fmaf(m2, p2.x, fmaf(m3, p3.x, acc[r][0])))); \
            acc[r][1] = fmaf(m0, p0.y, fmaf(m1, p1.y, fmaf(m2, p2.y, fmaf(m3, p3.y, acc[r][1])))); \
            acc[r][2] = fmaf(m0, p0.z, fmaf(m1, p1.z, fmaf(m2, p2.z, fmaf(m3, p3.z, acc[r][2])))); \
            acc[r][3] = fmaf(m0, p0.w, fmaf(m1, p1.w, fmaf(m2, p2.w, fmaf(m3, p3.w, acc[r][3])))); \
        }                                                                   \
    } while (0)

    const unsigned wq = (unsigned)qr * 16u;
    // W byte base for (tile-local field pg*4); half h adds h*256 fields = 16384B
    const unsigned wbase = (unsigned)(fbeg + pg * 4) * 64u + wq;

    STAGE(0, 0);

#pragma unroll 1
    for (int tl = 0; tl < NTF; ++tl) {
        // ---- all 8 W loads for this tile, issued before the wait ----
        const unsigned wB = wbase + (unsigned)tl * (TF * 64u);
        const float4 wa0 = *(const float4*)(Wb + wB);
        const float4 wa1 = *(const float4*)(Wb + wB + 64u);
        const float4 wa2 = *(const float4*)(Wb + wB + 128u);
        const float4 wa3 = *(const float4*)(Wb + wB + 192u);
        const float4 wb0 = *(const float4*)(Wb + wB + 16384u);
        const float4 wb1 = *(const float4*)(Wb + wB + 16384u + 64u);
        const float4 wb2 = *(const float4*)(Wb + wB + 16384u + 128u);
        const float4 wb3 = *(const float4*)(Wb + wB + 16384u + 192u);

        // retire S(tl) (4 ops), keep W(tl) (8 ops) in flight
        asm volatile("s_waitcnt vmcnt(8)" ::: "memory");
        __builtin_amdgcn_s_barrier();             // tile ready + buf-reuse guard
        __builtin_amdgcn_sched_barrier(0);

        if (tl + 1 < NTF) STAGE((tl + 1) & 1, tl + 1);
        __builtin_amdgcn_sched_barrier(0);        // pin S before later VMEM

        const int buf = tl & 1;
        FMTILE(wa0, wa1, wa2, wa3, (*(const int4*)&xbuf[buf][r][pg * 4]));
        FMTILE(wb0, wb1, wb2, wb3, (*(const int4*)&xbuf[buf][r][256 + pg * 4]));
        // no trailing sched_barrier: next-iter W loads may interleave with FMAs
    }

    // ---- tail: 212 fields, per-lane-uniform validity (212 = 53*4) ----
    {
        const bool valid = (pg < TAILPG);
        const int  pgc   = valid ? pg : (TAILPG - 1);
        const unsigned fb = (unsigned)(fbeg + NTF * TF + pgc * 4);
        const unsigned wT = fb * 64u + wq;
        float4 w0 = *(const float4*)(Wb + wT);
        float4 w1 = *(const float4*)(Wb + wT + 64u);
        float4 w2 = *(const float4*)(Wb + wT + 128u);
        float4 w3 = *(const float4*)(Wb + wT + 192u);
        if (!valid) {                             // zero W => zero contribution
            w0.x=w0.y=w0.z=w0.w=0.f; w1.x=w1.y=w1.z=w1.w=0.f;
            w2.x=w2.y=w2.z=w2.w=0.f; w3.x=w3.y=w3.z=w3.w=0.f;
        }
        FMTILE(w0, w1, w2, w3,
               (*(const int4*)(x0b + ((unsigned)(b0 + r) * FIELDS + fb) * 4u)));
    }

    // ---- wave reduce ----
    // acc: sum lanes sharing qr (xor 4..32). qac: sum ALL 64 lanes — each lane
    // accumulated only its own quarter's ssq, so q is counted exactly once.
#pragma unroll
    for (int r = 0; r < BT; ++r) {
#pragma unroll
        for (int off = 4; off < 64; off <<= 1) {
            acc[r][0] += __shfl_xor(acc[r][0], off);
            acc[r][1] += __shfl_xor(acc[r][1], off);
            acc[r][2] += __shfl_xor(acc[r][2], off);
            acc[r][3] += __shfl_xor(acc[r][3], off);
        }
#pragma unroll
        for (int off = 1; off < 64; off <<= 1)
            qac[r] += __shfl_xor(qac[r], off);
    }

    if (lane < 4) {                               // lane l holds quarter l
#pragma unroll
        for (int r = 0; r < BT; ++r) {
#pragma unroll
            for (int j = 0; j < 4; ++j)
                red[wv][r][lane * 4 + j] = acc[r][j];
            if (lane == 0) red[wv][r][16] = qac[r];
        }
    }
    __syncthreads();
    if (t < BT * 17) {
        const int r = t / 17;
        const int j = t % 17;
        const float v = red[0][r][j] + red[1][r][j] + red[2][r][j] + red[3][r][j];
        ws[((size_t)(b0 + r) * NCHUNK + chunk) * 17 + j] = v;
    }
#undef STAGE
#undef FMTILE
}

__global__ __launch_bounds__(BLOCK) void fm_final(
    const float* __restrict__ ws, float* __restrict__ out)
{
    const int b = blockIdx.x * BLOCK + threadIdx.x;
    if (b < BATCH) {
        const float* pbase = ws + (size_t)b * NCHUNK * 17;
        float s[17];
#pragma unroll
        for (int j = 0; j < 17; ++j) s[j] = 0.f;
#pragma unroll
        for (int c = 0; c < NCHUNK; ++c)
#pragma unroll
            for (int j = 0; j < 17; ++j) s[j] += pbase[c * 17 + j];
        float ss = 0.f;
#pragma unroll
        for (int k = 0; k < FACTORS; ++k) ss += s[k] * s[k];
        out[b] = 0.5f * (ss - s[16]);
    }
}

extern "C" void kernel_launch(void* const* d_in, const int* in_sizes, int n_in,
                              void* d_out, int out_size, void* d_ws, size_t ws_size,
                              hipStream_t stream)
{
    const int*   x0 = (const int*)d_in[0];
    const float* W  = (const float*)d_in[1];
    float* out = (float*)d_out;
    float* ws  = (float*)d_ws;   // [1024][8][17] floats, every slot written

    fm_partial<<<dim3((BATCH / BT) * NCHUNK), dim3(BLOCK), 0, stream>>>(x0, W, ws);
    fm_final<<<dim3((BATCH + BLOCK - 1) / BLOCK), dim3(BLOCK), 0, stream>>>(ws, out);
}